// Round 1
// baseline (964.160 us; speedup 1.0000x reference)
//
#include <hip/hip_runtime.h>
#include <math.h>

#define T_ 10
#define D_ 8
#define L_ 2
#define B_ 32768
#define H_ 64
#define NSAMP (T_ * B_)   // 327680

#define DEV static __device__ __forceinline__

DEV float shx(float v, int mask) { return __shfl_xor(v, mask, 64); }

// Precompute combined U = RZ(z) * RY(y) * RX(x) for each (l, wire).
// Layout: Us[(l*8+w)*8 + {u00r,u00i,u01r,u01i,u10r,u10i,u11r,u11i}]
__global__ void precompute_U(const float* __restrict__ params, float* __restrict__ Us) {
    int idx = threadIdx.x;
    if (idx >= L_ * D_) return;
    float ax = 0.5f * params[idx * 3 + 0];
    float ay = 0.5f * params[idx * 3 + 1];
    float az = 0.5f * params[idx * 3 + 2];
    float cx = cosf(ax), sx = sinf(ax);
    float cy = cosf(ay), sy = sinf(ay);
    float cz = cosf(az), sz = sinf(az);
    // M = RY(y)*RX(x):
    // M00 = cy*cx + i*sy*sx ; M01 = -sy*cx - i*cy*sx
    // M10 = sy*cx - i*cy*sx ; M11 =  cy*cx - i*sy*sx
    float m00r = cy * cx, m00i = sy * sx;
    float m01r = -sy * cx, m01i = -cy * sx;
    float m10r = sy * cx, m10i = -cy * sx;
    float m11r = cy * cx, m11i = -sy * sx;
    // U row0 = e^{-iz/2} * M row0 ; U row1 = e^{+iz/2} * M row1
    float u00r = cz * m00r + sz * m00i, u00i = cz * m00i - sz * m00r;
    float u01r = cz * m01r + sz * m01i, u01i = cz * m01i - sz * m01r;
    float u10r = cz * m10r - sz * m10i, u10i = cz * m10i + sz * m10r;
    float u11r = cz * m11r - sz * m11i, u11i = cz * m11i + sz * m11r;
    float* o = Us + idx * 8;
    o[0] = u00r; o[1] = u00i; o[2] = u01r; o[3] = u01i;
    o[4] = u10r; o[5] = u10i; o[6] = u11r; o[7] = u11i;
}

DEV void cgate(float u00r, float u00i, float u01r, float u01i,
               float u10r, float u10i, float u11r, float u11i,
               float& pr, float& pi, float& qr, float& qi) {
    float n0r = u00r * pr - u00i * pi + u01r * qr - u01i * qi;
    float n0i = u00r * pi + u00i * pr + u01r * qi + u01i * qr;
    float n1r = u10r * pr - u10i * pi + u11r * qr - u11i * qi;
    float n1i = u10r * pi + u10i * pr + u11r * qi + u11i * qr;
    pr = n0r; pi = n0i; qr = n1r; qi = n1i;
}

// One wave64 per sample. Amp index a (8 bits): bit0,bit1 = register index r,
// bits 2..7 = lane index. Wire w <-> bit w.
__global__ __launch_bounds__(256) void sim_kernel(const float* __restrict__ X,
                                                  const float* __restrict__ Us,
                                                  float* __restrict__ qf) {
    const int lane = threadIdx.x & 63;
    int n = (blockIdx.x << 2) + (threadIdx.x >> 6);
    n = __builtin_amdgcn_readfirstlane(n);
    const float* xr = X + n * 8;

    float sr[4], si[4];
#pragma unroll
    for (int r = 0; r < 4; ++r) { sr[r] = 0.f; si[r] = 0.f; }
    if (lane == 0) sr[0] = 1.f;

    // ---- encoding: RY(theta) then RZ(theta) on each wire, theta = X[n,w] ----
#pragma unroll
    for (int w = 0; w < 8; ++w) {
        float th = 0.5f * xr[w];
        float c = __cosf(th), s = __sinf(th);
        // RY
        if (w == 0) {
#pragma unroll
            for (int base = 0; base < 4; base += 2) {
                float ar = sr[base], ai = si[base], br = sr[base + 1], bi = si[base + 1];
                sr[base]     = c * ar - s * br;  si[base]     = c * ai - s * bi;
                sr[base + 1] = s * ar + c * br;  si[base + 1] = s * ai + c * bi;
            }
        } else if (w == 1) {
#pragma unroll
            for (int base = 0; base < 2; ++base) {
                float ar = sr[base], ai = si[base], br = sr[base + 2], bi = si[base + 2];
                sr[base]     = c * ar - s * br;  si[base]     = c * ai - s * bi;
                sr[base + 2] = s * ar + c * br;  si[base + 2] = s * ai + c * bi;
            }
        } else {
            const int mask = 1 << (w - 2);
            float se = ((lane >> (w - 2)) & 1) ? s : -s;
#pragma unroll
            for (int r = 0; r < 4; ++r) {
                float tr = shx(sr[r], mask), ti = shx(si[r], mask);
                sr[r] = c * sr[r] + se * tr;
                si[r] = c * si[r] + se * ti;
            }
        }
        // RZ (diagonal): amp *= e^{-i th} if bit==0 else e^{+i th}  (th = theta/2)
        if (w == 0) {
#pragma unroll
            for (int r = 0; r < 4; ++r) {
                float ze = (r & 1) ? -s : s;
                float re = sr[r], im = si[r];
                sr[r] = c * re + ze * im;
                si[r] = c * im - ze * re;
            }
        } else if (w == 1) {
#pragma unroll
            for (int r = 0; r < 4; ++r) {
                float ze = ((r >> 1) & 1) ? -s : s;
                float re = sr[r], im = si[r];
                sr[r] = c * re + ze * im;
                si[r] = c * im - ze * re;
            }
        } else {
            float ze = ((lane >> (w - 2)) & 1) ? -s : s;
#pragma unroll
            for (int r = 0; r < 4; ++r) {
                float re = sr[r], im = si[r];
                sr[r] = c * re + ze * im;
                si[r] = c * im - ze * re;
            }
        }
    }

    // ---- layers: combined U gates then CNOT ring ----
#pragma unroll
    for (int l = 0; l < L_; ++l) {
#pragma unroll
        for (int w = 0; w < 8; ++w) {
            const float* u = Us + (((l << 3) | w) << 3);
            float u00r = u[0], u00i = u[1], u01r = u[2], u01i = u[3];
            float u10r = u[4], u10i = u[5], u11r = u[6], u11i = u[7];
            if (w == 0) {
                cgate(u00r,u00i,u01r,u01i,u10r,u10i,u11r,u11i, sr[0],si[0],sr[1],si[1]);
                cgate(u00r,u00i,u01r,u01i,u10r,u10i,u11r,u11i, sr[2],si[2],sr[3],si[3]);
            } else if (w == 1) {
                cgate(u00r,u00i,u01r,u01i,u10r,u10i,u11r,u11i, sr[0],si[0],sr[2],si[2]);
                cgate(u00r,u00i,u01r,u01i,u10r,u10i,u11r,u11i, sr[1],si[1],sr[3],si[3]);
            } else {
                const int mask = 1 << (w - 2);
                const int m = (lane >> (w - 2)) & 1;
                float cAr = m ? u11r : u00r, cAi = m ? u11i : u00i;
                float cBr = m ? u10r : u01r, cBi = m ? u10i : u01i;
#pragma unroll
                for (int r = 0; r < 4; ++r) {
                    float tr = shx(sr[r], mask), ti = shx(si[r], mask);
                    float nr = cAr * sr[r] - cAi * si[r] + cBr * tr - cBi * ti;
                    float ni = cAr * si[r] + cAi * sr[r] + cBr * ti + cBi * tr;
                    sr[r] = nr; si[r] = ni;
                }
            }
        }
        // CNOT ring i -> (i+1) % 8, applied sequentially i = 0..7
        // i=0: CNOT(0,1): amps with bit0=1 flip bit1: swap r1 <-> r3 (register rename)
        { float t;
          t = sr[1]; sr[1] = sr[3]; sr[3] = t;
          t = si[1]; si[1] = si[3]; si[3] = t; }
        // i=1: CNOT(1,2): amps with bit1=1 (r=2,3) swap across lane bit0
        sr[2] = shx(sr[2], 1); si[2] = shx(si[2], 1);
        sr[3] = shx(sr[3], 1); si[3] = shx(si[3], 1);
        // i=2..6: CNOT(w, w+1): ctrl lane bit (w-2), tgt lane bit (w-1)
#pragma unroll
        for (int w = 2; w <= 6; ++w) {
            const int cb = (lane >> (w - 2)) & 1;
            const int tm = 1 << (w - 1);
#pragma unroll
            for (int r = 0; r < 4; ++r) {
                float tr = shx(sr[r], tm), ti = shx(si[r], tm);
                sr[r] = cb ? tr : sr[r];
                si[r] = cb ? ti : si[r];
            }
        }
        // i=7: CNOT(7,0): ctrl lane bit5, tgt bit0: swap (r0,r1) and (r2,r3)
        {
            const int cb = (lane >> 5) & 1;
            float a, b;
            a = cb ? sr[1] : sr[0]; b = cb ? sr[0] : sr[1]; sr[0] = a; sr[1] = b;
            a = cb ? si[1] : si[0]; b = cb ? si[0] : si[1]; si[0] = a; si[1] = b;
            a = cb ? sr[3] : sr[2]; b = cb ? sr[2] : sr[3]; sr[2] = a; sr[3] = b;
            a = cb ? si[3] : si[2]; b = cb ? si[2] : si[3]; si[2] = a; si[3] = b;
        }
    }

    // ---- measurement: <Z_w> ----
    float p0 = sr[0] * sr[0] + si[0] * si[0];
    float p1 = sr[1] * sr[1] + si[1] * si[1];
    float p2 = sr[2] * sr[2] + si[2] * si[2];
    float p3 = sr[3] * sr[3] + si[3] * si[3];
    float zA = p0 + p1 + p2 + p3;
    float v[8];
    v[0] = p0 - p1 + p2 - p3;   // wire0: bit0 = r&1
    v[1] = p0 + p1 - p2 - p3;   // wire1: bit1 = r>>1
#pragma unroll
    for (int w = 2; w < 8; ++w)
        v[w] = ((lane >> (w - 2)) & 1) ? -zA : zA;
#pragma unroll
    for (int w = 0; w < 8; ++w) {
#pragma unroll
        for (int m = 1; m < 64; m <<= 1)
            v[w] += shx(v[w], m);
    }
    if (lane == 0) {
        const int t = n >> 15;          // n / B
        const int b = n & (B_ - 1);     // n % B
        float* o = qf + b * (T_ * D_) + t * D_;
#pragma unroll
        for (int w = 0; w < 8; ++w) o[w] = v[w];
    }
}

// One wave64 per batch row: h = qf_row @ W1 + b1 ; LayerNorm(H=64) ; ReLU ; sigmoid(h @ W2 + b2)
__global__ __launch_bounds__(256) void head_kernel(const float* __restrict__ qf,
                                                   const float* __restrict__ W1,
                                                   const float* __restrict__ b1v,
                                                   const float* __restrict__ gam,
                                                   const float* __restrict__ bet,
                                                   const float* __restrict__ W2,
                                                   const float* __restrict__ b2v,
                                                   float* __restrict__ score) {
    const int lane = threadIdx.x & 63;
    int b = (blockIdx.x << 2) + (threadIdx.x >> 6);
    b = __builtin_amdgcn_readfirstlane(b);
    const float* row = qf + b * (T_ * D_);
    float h = b1v[lane];
#pragma unroll
    for (int k = 0; k < T_ * D_; ++k)
        h = fmaf(row[k], W1[(k << 6) + lane], h);
    float t = h;
#pragma unroll
    for (int m = 1; m < 64; m <<= 1) t += shx(t, m);
    float mu = t * (1.0f / 64.0f);
    float d = h - mu;
    float vv = d * d;
#pragma unroll
    for (int m = 1; m < 64; m <<= 1) vv += shx(vv, m);
    float rs = rsqrtf(vv * (1.0f / 64.0f) + 1e-5f);
    float hn = fmaxf(d * rs * gam[lane] + bet[lane], 0.f);
    float sacc = hn * W2[lane];
#pragma unroll
    for (int m = 1; m < 64; m <<= 1) sacc += shx(sacc, m);
    if (lane == 0) score[b] = 1.0f / (1.0f + expf(-(sacc + b2v[0])));
}

extern "C" void kernel_launch(void* const* d_in, const int* in_sizes, int n_in,
                              void* d_out, int out_size, void* d_ws, size_t ws_size,
                              hipStream_t stream) {
    const float* X_seq  = (const float*)d_in[0];
    const float* params = (const float*)d_in[1];
    const float* W1     = (const float*)d_in[2];
    const float* b1v    = (const float*)d_in[3];
    const float* gam    = (const float*)d_in[4];
    const float* bet    = (const float*)d_in[5];
    const float* W2     = (const float*)d_in[6];
    const float* b2v    = (const float*)d_in[7];

    float* out   = (float*)d_out;
    float* score = out;          // B floats
    float* qf    = out + B_;     // B*T*D floats
    float* Us    = (float*)d_ws; // 128 floats

    hipLaunchKernelGGL(precompute_U, dim3(1), dim3(64), 0, stream, params, Us);
    hipLaunchKernelGGL(sim_kernel, dim3(NSAMP / 4), dim3(256), 0, stream, X_seq, Us, qf);
    hipLaunchKernelGGL(head_kernel, dim3(B_ / 4), dim3(256), 0, stream,
                       qf, W1, b1v, gam, bet, W2, b2v, score);
}

// Round 2
// 580.549 us; speedup vs baseline: 1.6608x; 1.6608x over previous
//
#include <hip/hip_runtime.h>
#include <math.h>

#define T_ 10
#define D_ 8
#define L_ 2
#define B_ 32768
#define H_ 64
#define NSAMP (T_ * B_)   // 327680

#define DEV static __device__ __forceinline__

DEV float shx(float v, int mask) { return __shfl_xor(v, mask, 64); }

// Precompute combined U = RZ(z) * RY(y) * RX(x) for each (l, wire).
// Layout: Us[(l*8+w)*8 + {u00r,u00i,u01r,u01i,u10r,u10i,u11r,u11i}]
__global__ void precompute_U(const float* __restrict__ params, float* __restrict__ Us) {
    int idx = threadIdx.x;
    if (idx >= L_ * D_) return;
    float ax = 0.5f * params[idx * 3 + 0];
    float ay = 0.5f * params[idx * 3 + 1];
    float az = 0.5f * params[idx * 3 + 2];
    float cx = cosf(ax), sx = sinf(ax);
    float cy = cosf(ay), sy = sinf(ay);
    float cz = cosf(az), sz = sinf(az);
    // M = RY(y)*RX(x)
    float m00r = cy * cx, m00i = sy * sx;
    float m01r = -sy * cx, m01i = -cy * sx;
    float m10r = sy * cx, m10i = -cy * sx;
    float m11r = cy * cx, m11i = -sy * sx;
    // U row0 = e^{-iz/2} * M row0 ; U row1 = e^{+iz/2} * M row1
    float u00r = cz * m00r + sz * m00i, u00i = cz * m00i - sz * m00r;
    float u01r = cz * m01r + sz * m01i, u01i = cz * m01i - sz * m01r;
    float u10r = cz * m10r - sz * m10i, u10i = cz * m10i + sz * m10r;
    float u11r = cz * m11r - sz * m11i, u11i = cz * m11i + sz * m11r;
    float* o = Us + idx * 8;
    o[0] = u00r; o[1] = u00i; o[2] = u01r; o[3] = u01i;
    o[4] = u10r; o[5] = u10i; o[6] = u11r; o[7] = u11i;
}

DEV void cgate(float u00r, float u00i, float u01r, float u01i,
               float u10r, float u10i, float u11r, float u11i,
               float& pr, float& pi, float& qr, float& qi) {
    float n0r = u00r * pr - u00i * pi + u01r * qr - u01i * qi;
    float n0i = u00r * pi + u00i * pr + u01r * qi + u01i * qr;
    float n1r = u10r * pr - u10i * pi + u11r * qr - u11i * qi;
    float n1i = u10r * pi + u10i * pr + u11r * qi + u11i * qr;
    pr = n0r; pi = n0i; qr = n1r; qi = n1i;
}

// One wave64 per sample. Amp index i (8 bits): i0,i1 = register index r = i0+2*i1,
// bits 2..7 = lane bits. Wire w <-> bit w.
__global__ __launch_bounds__(256) void sim_kernel(const float* __restrict__ X,
                                                  const float* __restrict__ Us,
                                                  float* __restrict__ qf) {
    const int lane = threadIdx.x & 63;
    int n = (blockIdx.x << 2) + (threadIdx.x >> 6);
    n = __builtin_amdgcn_readfirstlane(n);
    const float* xr = X + n * 8;

    float sr[4], si[4];

    // ---- encoding: product state. Per wire factor after RY(th)RZ(th) on |0>:
    // f(0) = (c^2, -c s), f(1) = (c s, s^2), c=cos(th/2), s=sin(th/2). ----
    float Pr = 1.f, Pi = 0.f;
#pragma unroll
    for (int w = 2; w < 8; ++w) {
        float th = 0.5f * xr[w];
        float c = __cosf(th), s = __sinf(th);
        float cc = c * c, cs = c * s, ss = s * s;
        int bit = (lane >> (w - 2)) & 1;
        float fr = bit ? cs : cc;
        float fi = bit ? ss : -cs;
        float nr = Pr * fr - Pi * fi;
        float ni = Pr * fi + Pi * fr;
        Pr = nr; Pi = ni;
    }
    {
        float th0 = 0.5f * xr[0], c0 = __cosf(th0), s0 = __sinf(th0);
        float th1 = 0.5f * xr[1], c1 = __cosf(th1), s1 = __sinf(th1);
        float f0r[2] = { c0 * c0, c0 * s0 }, f0i[2] = { -c0 * s0, s0 * s0 };
        float f1r[2] = { c1 * c1, c1 * s1 }, f1i[2] = { -c1 * s1, s1 * s1 };
#pragma unroll
        for (int r = 0; r < 4; ++r) {
            int b0 = r & 1, b1 = (r >> 1) & 1;
            float gr = f0r[b0] * f1r[b1] - f0i[b0] * f1i[b1];
            float gi = f0r[b0] * f1i[b1] + f0i[b0] * f1r[b1];
            sr[r] = Pr * gr - Pi * gi;
            si[r] = Pr * gi + Pi * gr;
        }
    }

    // ---- layers: combined U gates then CNOT ring ----
#pragma unroll
    for (int l = 0; l < L_; ++l) {
#pragma unroll
        for (int w = 0; w < 8; ++w) {
            const float* u = Us + (((l << 3) | w) << 3);
            float u00r = u[0], u00i = u[1], u01r = u[2], u01i = u[3];
            float u10r = u[4], u10i = u[5], u11r = u[6], u11i = u[7];
            if (w == 0) {
                cgate(u00r,u00i,u01r,u01i,u10r,u10i,u11r,u11i, sr[0],si[0],sr[1],si[1]);
                cgate(u00r,u00i,u01r,u01i,u10r,u10i,u11r,u11i, sr[2],si[2],sr[3],si[3]);
            } else if (w == 1) {
                cgate(u00r,u00i,u01r,u01i,u10r,u10i,u11r,u11i, sr[0],si[0],sr[2],si[2]);
                cgate(u00r,u00i,u01r,u01i,u10r,u10i,u11r,u11i, sr[1],si[1],sr[3],si[3]);
            } else {
                const int mask = 1 << (w - 2);
                const int m = (lane >> (w - 2)) & 1;
                float cAr = m ? u11r : u00r, cAi = m ? u11i : u00i;
                float cBr = m ? u10r : u01r, cBi = m ? u10i : u01i;
#pragma unroll
                for (int r = 0; r < 4; ++r) {
                    float tr = shx(sr[r], mask), ti = shx(si[r], mask);
                    float nr = cAr * sr[r] - cAi * si[r] + cBr * tr - cBi * ti;
                    float ni = cAr * si[r] + cAi * sr[r] + cBr * ti + cBi * tr;
                    sr[r] = nr; si[r] = ni;
                }
            }
        }
        // CNOT ring i->(i+1)%8 as one linear permutation:
        // src index j of target i: j0=i0^i7, j1=i1^i0^i7, jk=ik^i(k-1) (k>=2).
        // => src_lane = ((lane ^ (lane<<1)) & 63) ^ i1 ; src_reg per table below.
        {
            const int S0v = (lane ^ (lane << 1)) & 63;
            const int S1v = S0v ^ 1;
            const bool l5 = (lane & 32) != 0;
            float a0r = __shfl(sr[0], S0v, 64), a0i = __shfl(si[0], S0v, 64);
            float a3r = __shfl(sr[3], S0v, 64), a3i = __shfl(si[3], S0v, 64);
            float a1r = __shfl(sr[1], S1v, 64), a1i = __shfl(si[1], S1v, 64);
            float a2r = __shfl(sr[2], S1v, 64), a2i = __shfl(si[2], S1v, 64);
            sr[0] = l5 ? a3r : a0r;  si[0] = l5 ? a3i : a0i;
            sr[1] = l5 ? a0r : a3r;  si[1] = l5 ? a0i : a3i;
            sr[2] = l5 ? a1r : a2r;  si[2] = l5 ? a1i : a2i;
            sr[3] = l5 ? a2r : a1r;  si[3] = l5 ? a2i : a1i;
        }
    }

    // ---- measurement: <Z_w> ----
    float p0 = sr[0] * sr[0] + si[0] * si[0];
    float p1 = sr[1] * sr[1] + si[1] * si[1];
    float p2 = sr[2] * sr[2] + si[2] * si[2];
    float p3 = sr[3] * sr[3] + si[3] * si[3];
    float d = p0 + p1, e = p2 + p3;
    float zA  = d + e;                    // per-lane prob mass
    float v1l = d - e;                    // wire 1 local
    float v0l = (p0 + p2) - (p1 + p3);    // wire 0 local

    // Walsh-Hadamard butterfly on zA: after 6 steps lane k holds
    // sum_l (-1)^{popcount(l&k)} zA_l ; lanes 1,2,4,8,16,32 = v[2..7].
    float x = zA;
#pragma unroll
    for (int m = 1; m < 64; m <<= 1) {
        float t = shx(x, m);
        x = (lane & m) ? (t - x) : (x + t);
    }
    // plain full sums for wires 0,1
#pragma unroll
    for (int m = 1; m < 64; m <<= 1) {
        v0l += shx(v0l, m);
        v1l += shx(v1l, m);
    }

    const int t_ = n >> 15;          // n / B
    const int b_ = n & (B_ - 1);     // n % B
    float* o = qf + b_ * (T_ * D_) + t_ * D_;
    if (lane == 0) { o[0] = v0l; o[1] = v1l; }
    if (lane && !(lane & (lane - 1))) {
        o[2 + (__ffs(lane) - 1)] = x;
    }
}

// One wave64 per batch row: h = qf_row @ W1 + b1 ; LayerNorm(H=64) ; ReLU ; sigmoid(h @ W2 + b2)
__global__ __launch_bounds__(256) void head_kernel(const float* __restrict__ qf,
                                                   const float* __restrict__ W1,
                                                   const float* __restrict__ b1v,
                                                   const float* __restrict__ gam,
                                                   const float* __restrict__ bet,
                                                   const float* __restrict__ W2,
                                                   const float* __restrict__ b2v,
                                                   float* __restrict__ score) {
    const int lane = threadIdx.x & 63;
    int b = (blockIdx.x << 2) + (threadIdx.x >> 6);
    b = __builtin_amdgcn_readfirstlane(b);
    const float* row = qf + b * (T_ * D_);
    float h = b1v[lane];
#pragma unroll
    for (int k = 0; k < T_ * D_; ++k)
        h = fmaf(row[k], W1[(k << 6) + lane], h);
    float t = h;
#pragma unroll
    for (int m = 1; m < 64; m <<= 1) t += shx(t, m);
    float mu = t * (1.0f / 64.0f);
    float d = h - mu;
    float vv = d * d;
#pragma unroll
    for (int m = 1; m < 64; m <<= 1) vv += shx(vv, m);
    float rs = rsqrtf(vv * (1.0f / 64.0f) + 1e-5f);
    float hn = fmaxf(d * rs * gam[lane] + bet[lane], 0.f);
    float sacc = hn * W2[lane];
#pragma unroll
    for (int m = 1; m < 64; m <<= 1) sacc += shx(sacc, m);
    if (lane == 0) score[b] = 1.0f / (1.0f + expf(-(sacc + b2v[0])));
}

extern "C" void kernel_launch(void* const* d_in, const int* in_sizes, int n_in,
                              void* d_out, int out_size, void* d_ws, size_t ws_size,
                              hipStream_t stream) {
    const float* X_seq  = (const float*)d_in[0];
    const float* params = (const float*)d_in[1];
    const float* W1     = (const float*)d_in[2];
    const float* b1v    = (const float*)d_in[3];
    const float* gam    = (const float*)d_in[4];
    const float* bet    = (const float*)d_in[5];
    const float* W2     = (const float*)d_in[6];
    const float* b2v    = (const float*)d_in[7];

    float* out   = (float*)d_out;
    float* score = out;          // B floats
    float* qf    = out + B_;     // B*T*D floats
    float* Us    = (float*)d_ws; // 128 floats

    hipLaunchKernelGGL(precompute_U, dim3(1), dim3(64), 0, stream, params, Us);
    hipLaunchKernelGGL(sim_kernel, dim3(NSAMP / 4), dim3(256), 0, stream, X_seq, Us, qf);
    hipLaunchKernelGGL(head_kernel, dim3(B_ / 4), dim3(256), 0, stream,
                       qf, W1, b1v, gam, bet, W2, b2v, score);
}

// Round 6
// 373.555 us; speedup vs baseline: 2.5810x; 1.5541x over previous
//
#include <hip/hip_runtime.h>
#include <math.h>

#define T_ 10
#define D_ 8
#define L_ 2
#define B_ 32768
#define NSAMP (T_ * B_)   // 327680

#define DEV static __device__ __forceinline__

template<int CTRL>
DEV float dpp_mov(float x) {
    return __int_as_float(__builtin_amdgcn_mov_dpp(__float_as_int(x), CTRL, 0xF, 0xF, true));
}

template<int OFF>
DEV float swz(float x) {
    return __int_as_float(__builtin_amdgcn_ds_swizzle(__float_as_int(x), OFF));
}

// exchange across amp-bit W (lane bit W-2).
// W=7 (xor32): __shfl_xor / ds_bpermute — the R0/R1-proven path.
// (v_permlane32_swap_b32 was tried in R2-R4; three semantic models all
// failed on HW — abandoned pending disasm evidence.)
template<int W>
DEV float exch(float x) {
    if constexpr (W == 2) return dpp_mov<0xB1>(x);        // quad_perm(1,0,3,2) = xor1
    else if constexpr (W == 3) return dpp_mov<0x4E>(x);   // quad_perm(2,3,0,1) = xor2
    else if constexpr (W == 4) return swz<0x101F>(x);     // ds_swizzle xor4
    else if constexpr (W == 5) return dpp_mov<0x128>(x);  // row_ror:8 = xor8
    else if constexpr (W == 6) return swz<0x401F>(x);     // ds_swizzle xor16
    else return __shfl_xor(x, 32, 64);                    // xor32 via bpermute
}

// Precompute combined U = RZ(z)*RY(y)*RX(x) per (l, wire).
__global__ void precompute_U(const float* __restrict__ params, float* __restrict__ Us) {
    int idx = threadIdx.x;
    if (idx >= L_ * D_) return;
    float ax = 0.5f * params[idx * 3 + 0];
    float ay = 0.5f * params[idx * 3 + 1];
    float az = 0.5f * params[idx * 3 + 2];
    float cx = cosf(ax), sx = sinf(ax);
    float cy = cosf(ay), sy = sinf(ay);
    float cz = cosf(az), sz = sinf(az);
    float m00r = cy * cx, m00i = sy * sx;
    float m01r = -sy * cx, m01i = -cy * sx;
    float m10r = sy * cx, m10i = -cy * sx;
    float m11r = cy * cx, m11i = -sy * sx;
    float u00r = cz * m00r + sz * m00i, u00i = cz * m00i - sz * m00r;
    float u01r = cz * m01r + sz * m01i, u01i = cz * m01i - sz * m01r;
    float u10r = cz * m10r - sz * m10i, u10i = cz * m10i + sz * m10r;
    float u11r = cz * m11r - sz * m11i, u11i = cz * m11i + sz * m11r;
    float* o = Us + idx * 8;
    o[0] = u00r; o[1] = u00i; o[2] = u01r; o[3] = u01i;
    o[4] = u10r; o[5] = u10i; o[6] = u11r; o[7] = u11i;
}

DEV void cgate(float u00r, float u00i, float u01r, float u01i,
               float u10r, float u10i, float u11r, float u11i,
               float& pr, float& pi, float& qr, float& qi) {
    float n0r = u00r * pr - u00i * pi + u01r * qr - u01i * qi;
    float n0i = u00r * pi + u00i * pr + u01r * qi + u01i * qr;
    float n1r = u10r * pr - u10i * pi + u11r * qr - u11i * qi;
    float n1i = u10r * pi + u10i * pr + u11r * qi + u11i * qr;
    pr = n0r; pi = n0i; qr = n1r; qi = n1i;
}

template<int W>
DEV void lane_gate(const float* __restrict__ u, int lane, float (&sr)[4], float (&si)[4]) {
    const int m = (lane >> (W - 2)) & 1;
    float cAr = m ? u[6] : u[0], cAi = m ? u[7] : u[1];
    float cBr = m ? u[4] : u[2], cBi = m ? u[5] : u[3];
#pragma unroll
    for (int r = 0; r < 4; ++r) {
        float tr = exch<W>(sr[r]), ti = exch<W>(si[r]);
        float nr = cAr * sr[r] - cAi * si[r] + cBr * tr - cBi * ti;
        float ni = cAr * si[r] + cAi * sr[r] + cBr * ti + cBi * tr;
        sr[r] = nr; si[r] = ni;
    }
}

DEV void gate_layer(const float* __restrict__ Ul, int lane, float (&sr)[4], float (&si)[4]) {
    {
        const float* u = Ul;
        cgate(u[0],u[1],u[2],u[3],u[4],u[5],u[6],u[7], sr[0],si[0],sr[1],si[1]);
        cgate(u[0],u[1],u[2],u[3],u[4],u[5],u[6],u[7], sr[2],si[2],sr[3],si[3]);
    }
    {
        const float* u = Ul + 8;
        cgate(u[0],u[1],u[2],u[3],u[4],u[5],u[6],u[7], sr[0],si[0],sr[2],si[2]);
        cgate(u[0],u[1],u[2],u[3],u[4],u[5],u[6],u[7], sr[1],si[1],sr[3],si[3]);
    }
    lane_gate<2>(Ul + 16, lane, sr, si);
    lane_gate<3>(Ul + 24, lane, sr, si);
    lane_gate<4>(Ul + 32, lane, sr, si);
    lane_gate<5>(Ul + 40, lane, sr, si);
    lane_gate<6>(Ul + 48, lane, sr, si);
    lane_gate<7>(Ul + 56, lane, sr, si);
}

// One wave64 per sample. Amp index i: i0,i1 = register bits (r = i0 + 2*i1),
// i2..i7 = lane bits 0..5.
__global__ __launch_bounds__(256) void sim_kernel(const float* __restrict__ X,
                                                  const float* __restrict__ Us,
                                                  float* __restrict__ qf) {
    const int lane = threadIdx.x & 63;
    int n = (blockIdx.x << 2) + (threadIdx.x >> 6);
    n = __builtin_amdgcn_readfirstlane(n);
    const float* xr = X + n * 8;

    float sr[4], si[4];

    // ---- encoding: product state. f(0)=(c^2,-cs), f(1)=(cs,s^2) per wire ----
    float Pr = 1.f, Pi = 0.f;
#pragma unroll
    for (int w = 2; w < 8; ++w) {
        float th = 0.5f * xr[w];
        float c = __cosf(th), s = __sinf(th);
        float cc = c * c, cs = c * s, ss = s * s;
        int bit = (lane >> (w - 2)) & 1;
        float fr = bit ? cs : cc;
        float fi = bit ? ss : -cs;
        float nr = Pr * fr - Pi * fi;
        float ni = Pr * fi + Pi * fr;
        Pr = nr; Pi = ni;
    }
    {
        float th0 = 0.5f * xr[0], c0 = __cosf(th0), s0 = __sinf(th0);
        float th1 = 0.5f * xr[1], c1 = __cosf(th1), s1 = __sinf(th1);
        float f0r[2] = { c0 * c0, c0 * s0 }, f0i[2] = { -c0 * s0, s0 * s0 };
        float f1r[2] = { c1 * c1, c1 * s1 }, f1i[2] = { -c1 * s1, s1 * s1 };
#pragma unroll
        for (int r = 0; r < 4; ++r) {
            int b0 = r & 1, b1 = (r >> 1) & 1;
            float gr = f0r[b0] * f1r[b1] - f0i[b0] * f1i[b1];
            float gi = f0r[b0] * f1i[b1] + f0i[b0] * f1r[b1];
            sr[r] = Pr * gr - Pi * gi;
            si[r] = Pr * gi + Pi * gr;
        }
    }

    // ---- layer 0: gates + CNOT ring ----
    gate_layer(Us, lane, sr, si);
    {
        // ring i->(i+1)%8: src j of target i: j0=i0^i7, j1=i1^i0^i7, jk=ik^i(k-1)
        const int S0v = (lane ^ (lane << 1)) & 63;
        const int S1v = S0v ^ 1;
        const bool l5 = (lane & 32) != 0;
        float a0r = __shfl(sr[0], S0v, 64), a0i = __shfl(si[0], S0v, 64);
        float a3r = __shfl(sr[3], S0v, 64), a3i = __shfl(si[3], S0v, 64);
        float a1r = __shfl(sr[1], S1v, 64), a1i = __shfl(si[1], S1v, 64);
        float a2r = __shfl(sr[2], S1v, 64), a2i = __shfl(si[2], S1v, 64);
        sr[0] = l5 ? a3r : a0r;  si[0] = l5 ? a3i : a0i;
        sr[1] = l5 ? a0r : a3r;  si[1] = l5 ? a0i : a3i;
        sr[2] = l5 ? a1r : a2r;  si[2] = l5 ? a1i : a2i;
        sr[3] = l5 ? a2r : a1r;  si[3] = l5 ? a2i : a1i;
    }

    // ---- layer 1: gates only; final ring absorbed into measurement ----
    gate_layer(Us + 64, lane, sr, si);

    // ---- measurement (post-ring Z_w == pre-ring Walsh masks) ----
    // Verified by basis-state cases: |0..0>, wire0=1, wire2=1.
    // M_0: reg sign (-1)^{i1}, lane parity sign, full sum.
    // M_w (w=1..7): reg sign (-1)^{i0^i1}, lane masks {0,1,3,7,15,31,63}.
    float p0 = sr[0] * sr[0] + si[0] * si[0];
    float p1 = sr[1] * sr[1] + si[1] * si[1];
    float p2 = sr[2] * sr[2] + si[2] * si[2];
    float p3 = sr[3] * sr[3] + si[3] * si[3];
    float local0  = (p0 + p1) - (p2 + p3);   // (-1)^{i1}
    float local12 = (p0 - p1) - (p2 - p3);   // (-1)^{i0^i1}

    // v[0]: parity-signed full sum of local0
    float a = (__popc(lane) & 1) ? -local0 : local0;
    a += exch<2>(a); a += exch<3>(a); a += exch<4>(a);
    a += exch<5>(a); a += exch<6>(a); a += exch<7>(a);

    // signed WHT butterfly on local12: lane k ends with coeff of mask k
    float x = local12;
    { float t = exch<2>(x); x = (lane & 1)  ? (t - x) : (x + t); }
    { float t = exch<3>(x); x = (lane & 2)  ? (t - x) : (x + t); }
    { float t = exch<4>(x); x = (lane & 4)  ? (t - x) : (x + t); }
    { float t = exch<5>(x); x = (lane & 8)  ? (t - x) : (x + t); }
    { float t = exch<6>(x); x = (lane & 16) ? (t - x) : (x + t); }
    { float t = exch<7>(x); x = (lane & 32) ? (t - x) : (x + t); }

    const int t_ = n >> 15;          // n / B
    const int b_ = n & (B_ - 1);     // n % B
    float* o = qf + b_ * (T_ * D_) + t_ * D_;
    if ((lane & (lane + 1)) == 0) {  // lanes 0,1,3,7,15,31,63
        o[1 + __popc(lane)] = x;     // w = 1..7
        if (lane == 63) o[0] = a;    // w = 0
    }
}

// One wave64 per batch row: h = qf_row @ W1 + b1 ; LayerNorm ; ReLU ; sigmoid(h @ W2 + b2)
__global__ __launch_bounds__(256) void head_kernel(const float* __restrict__ qf,
                                                   const float* __restrict__ W1,
                                                   const float* __restrict__ b1v,
                                                   const float* __restrict__ gam,
                                                   const float* __restrict__ bet,
                                                   const float* __restrict__ W2,
                                                   const float* __restrict__ b2v,
                                                   float* __restrict__ score) {
    const int lane = threadIdx.x & 63;
    int b = (blockIdx.x << 2) + (threadIdx.x >> 6);
    b = __builtin_amdgcn_readfirstlane(b);
    const float* row = qf + b * (T_ * D_);
    float h = b1v[lane];
#pragma unroll
    for (int k = 0; k < T_ * D_; ++k)
        h = fmaf(row[k], W1[(k << 6) + lane], h);
    float t = h;
#pragma unroll
    for (int m = 1; m < 64; m <<= 1) t += __shfl_xor(t, m, 64);
    float mu = t * (1.0f / 64.0f);
    float d = h - mu;
    float vv = d * d;
#pragma unroll
    for (int m = 1; m < 64; m <<= 1) vv += __shfl_xor(vv, m, 64);
    float rs = rsqrtf(vv * (1.0f / 64.0f) + 1e-5f);
    float hn = fmaxf(d * rs * gam[lane] + bet[lane], 0.f);
    float sacc = hn * W2[lane];
#pragma unroll
    for (int m = 1; m < 64; m <<= 1) sacc += __shfl_xor(sacc, m, 64);
    if (lane == 0) score[b] = 1.0f / (1.0f + expf(-(sacc + b2v[0])));
}

extern "C" void kernel_launch(void* const* d_in, const int* in_sizes, int n_in,
                              void* d_out, int out_size, void* d_ws, size_t ws_size,
                              hipStream_t stream) {
    const float* X_seq  = (const float*)d_in[0];
    const float* params = (const float*)d_in[1];
    const float* W1     = (const float*)d_in[2];
    const float* b1v    = (const float*)d_in[3];
    const float* gam    = (const float*)d_in[4];
    const float* bet    = (const float*)d_in[5];
    const float* W2     = (const float*)d_in[6];
    const float* b2v    = (const float*)d_in[7];

    float* out   = (float*)d_out;
    float* score = out;          // B floats
    float* qf    = out + B_;     // B*T*D floats
    float* Us    = (float*)d_ws; // 128 floats

    hipLaunchKernelGGL(precompute_U, dim3(1), dim3(64), 0, stream, params, Us);
    hipLaunchKernelGGL(sim_kernel, dim3(NSAMP / 4), dim3(256), 0, stream, X_seq, Us, qf);
    hipLaunchKernelGGL(head_kernel, dim3(B_ / 4), dim3(256), 0, stream,
                       qf, W1, b1v, gam, bet, W2, b2v, score);
}

// Round 8
// 296.389 us; speedup vs baseline: 3.2530x; 1.2604x over previous
//
#include <hip/hip_runtime.h>
#include <math.h>

#define T_ 10
#define D_ 8
#define L_ 2
#define B_ 32768
#define NSAMP (T_ * B_)   // 327680

#define DEV static __device__ __forceinline__

template<int CTRL>
DEV float dpp_mov(float x) {
    return __int_as_float(__builtin_amdgcn_mov_dpp(__float_as_int(x), CTRL, 0xF, 0xF, true));
}

template<int OFF>
DEV float swz(float x) {
    return __int_as_float(__builtin_amdgcn_ds_swizzle(__float_as_int(x), OFF));
}

// exchange across amp-bit W (lane bit W-2).
// All controls here are R6-HW-proven on gfx950. (row_ror:4/12 xor4 remap was
// tried in R7 and failed: row_ror:N reads lane i-N, my select assumed i+N —
// reverted to the proven swizzle; rotation-direction tricks need disasm
// evidence first.)
template<int W>
DEV float exch(float x) {
    if constexpr (W == 2) return dpp_mov<0xB1>(x);        // quad_perm(1,0,3,2) = xor1
    else if constexpr (W == 3) return dpp_mov<0x4E>(x);   // quad_perm(2,3,0,1) = xor2
    else if constexpr (W == 4) return swz<0x101F>(x);     // ds_swizzle xor4
    else if constexpr (W == 5) return dpp_mov<0x128>(x);  // row_ror:8 = xor8 (direction-symmetric)
    else if constexpr (W == 6) return swz<0x401F>(x);     // ds_swizzle xor16
    else return __shfl_xor(x, 32, 64);                    // xor32 via bpermute
}

// Precompute combined U = RZ(z)*RY(y)*RX(x) per (l, wire).
__global__ void precompute_U(const float* __restrict__ params, float* __restrict__ Us) {
    int idx = threadIdx.x;
    if (idx >= L_ * D_) return;
    float ax = 0.5f * params[idx * 3 + 0];
    float ay = 0.5f * params[idx * 3 + 1];
    float az = 0.5f * params[idx * 3 + 2];
    float cx = cosf(ax), sx = sinf(ax);
    float cy = cosf(ay), sy = sinf(ay);
    float cz = cosf(az), sz = sinf(az);
    float m00r = cy * cx, m00i = sy * sx;
    float m01r = -sy * cx, m01i = -cy * sx;
    float m10r = sy * cx, m10i = -cy * sx;
    float m11r = cy * cx, m11i = -sy * sx;
    float u00r = cz * m00r + sz * m00i, u00i = cz * m00i - sz * m00r;
    float u01r = cz * m01r + sz * m01i, u01i = cz * m01i - sz * m01r;
    float u10r = cz * m10r - sz * m10i, u10i = cz * m10i + sz * m10r;
    float u11r = cz * m11r - sz * m11i, u11i = cz * m11i + sz * m11r;
    float* o = Us + idx * 8;
    o[0] = u00r; o[1] = u00i; o[2] = u01r; o[3] = u01i;
    o[4] = u10r; o[5] = u10i; o[6] = u11r; o[7] = u11i;
}

DEV void cgate(float u00r, float u00i, float u01r, float u01i,
               float u10r, float u10i, float u11r, float u11i,
               float& pr, float& pi, float& qr, float& qi) {
    float n0r = u00r * pr - u00i * pi + u01r * qr - u01i * qi;
    float n0i = u00r * pi + u00i * pr + u01r * qi + u01i * qr;
    float n1r = u10r * pr - u10i * pi + u11r * qr - u11i * qi;
    float n1i = u10r * pi + u10i * pr + u11r * qi + u11i * qr;
    pr = n0r; pi = n0i; qr = n1r; qi = n1i;
}

template<int W>
DEV void lane_gate(const float* __restrict__ u, int lane, float (&sr)[4], float (&si)[4]) {
    const int m = (lane >> (W - 2)) & 1;
    float cAr = m ? u[6] : u[0], cAi = m ? u[7] : u[1];
    float cBr = m ? u[4] : u[2], cBi = m ? u[5] : u[3];
#pragma unroll
    for (int r = 0; r < 4; ++r) {
        float tr = exch<W>(sr[r]), ti = exch<W>(si[r]);
        float nr = cAr * sr[r] - cAi * si[r] + cBr * tr - cBi * ti;
        float ni = cAr * si[r] + cAi * sr[r] + cBr * ti + cBi * tr;
        sr[r] = nr; si[r] = ni;
    }
}

DEV void gate_layer(const float* __restrict__ Ul, int lane, float (&sr)[4], float (&si)[4]) {
    {
        const float* u = Ul;
        cgate(u[0],u[1],u[2],u[3],u[4],u[5],u[6],u[7], sr[0],si[0],sr[1],si[1]);
        cgate(u[0],u[1],u[2],u[3],u[4],u[5],u[6],u[7], sr[2],si[2],sr[3],si[3]);
    }
    {
        const float* u = Ul + 8;
        cgate(u[0],u[1],u[2],u[3],u[4],u[5],u[6],u[7], sr[0],si[0],sr[2],si[2]);
        cgate(u[0],u[1],u[2],u[3],u[4],u[5],u[6],u[7], sr[1],si[1],sr[3],si[3]);
    }
    lane_gate<2>(Ul + 16, lane, sr, si);
    lane_gate<3>(Ul + 24, lane, sr, si);
    lane_gate<4>(Ul + 32, lane, sr, si);
    lane_gate<5>(Ul + 40, lane, sr, si);
    lane_gate<6>(Ul + 48, lane, sr, si);
    lane_gate<7>(Ul + 56, lane, sr, si);
}

// One wave64 per sample. Amp index i: i0,i1 = register bits (r = i0 + 2*i1),
// i2..i7 = lane bits 0..5.
//
// Structure: |0..0> --RY,RZ encode--> product state ⊗v_w
//            --layer-0 gates--> still product: v'_w = U_w v_w      (free fold)
//            --ring-0--> permuted product: psi[i] = prod_w v'_w[j_w(i)]
//               j0=i0^i7, j1=i1^i0^i7, jk=ik^i(k-1)                (free fold)
//            --layer-1 gates--> (genuine exchanges)
//            --ring-1 + measure--> Walsh masks on probs            (R6-proven)
__global__ __launch_bounds__(256) void sim_kernel(const float* __restrict__ X,
                                                  const float* __restrict__ Us,
                                                  float* __restrict__ qf) {
    const int lane = threadIdx.x & 63;
    int n = (blockIdx.x << 2) + (threadIdx.x >> 6);
    n = __builtin_amdgcn_readfirstlane(n);
    const float* xr = X + n * 8;

    // ---- per-wire 2-vectors after encoding + layer-0 gate (wave-uniform) ----
    // v_w = ((c^2,-cs),(cs,s^2)) ; v'_w = U0_w v_w.
    float w0r[3], w0i[3], w1r[3], w1i[3];  // wires 0,1,2 kept componentwise
    float CPr = 0.f, CPi = 0.f;            // product over wires 3..7 (per lane)
#pragma unroll
    for (int w = 0; w < 8; ++w) {
        float th = 0.5f * xr[w];
        float c = __cosf(th), s = __sinf(th);
        float a0r = c * c, a0i = -c * s, a1r = c * s, a1i = s * s;
        const float* u = Us + (w << 3);   // layer-0 U
        float f0r = u[0] * a0r - u[1] * a0i + u[2] * a1r - u[3] * a1i;
        float f0i = u[0] * a0i + u[1] * a0r + u[2] * a1i + u[3] * a1r;
        float f1r = u[4] * a0r - u[5] * a0i + u[6] * a1r - u[7] * a1i;
        float f1i = u[4] * a0i + u[5] * a0r + u[6] * a1i + u[7] * a1r;
        if (w < 3) {
            w0r[w] = f0r; w0i[w] = f0i; w1r[w] = f1r; w1i[w] = f1i;
        } else {
            // j_w = i_w ^ i_(w-1) = lane bit (w-2) ^ lane bit (w-3)
            int j = ((lane >> (w - 2)) ^ (lane >> (w - 3))) & 1;
            float fr = j ? f1r : f0r, fi = j ? f1i : f0i;
            if (w == 3) { CPr = fr; CPi = fi; }
            else {
                float nr = CPr * fr - CPi * fi;
                CPi = CPr * fi + CPi * fr;
                CPr = nr;
            }
        }
    }

    // CPa/b = CP * v'_2[0/1]  (wire-2 factor: j2 = l0 ^ i1)
    float CPar = CPr * w0r[2] - CPi * w0i[2], CPai = CPr * w0i[2] + CPi * w0r[2];
    float CPbr = CPr * w1r[2] - CPi * w1i[2], CPbi = CPr * w1i[2] + CPi * w1r[2];
    // P(a,b) = v'_0[a] * v'_1[b]
    float P00r = w0r[0] * w0r[1] - w0i[0] * w0i[1], P00i = w0r[0] * w0i[1] + w0i[0] * w0r[1];
    float P01r = w0r[0] * w1r[1] - w0i[0] * w1i[1], P01i = w0r[0] * w1i[1] + w0i[0] * w1r[1];
    float P10r = w1r[0] * w0r[1] - w1i[0] * w0i[1], P10i = w1r[0] * w0i[1] + w1i[0] * w0r[1];
    float P11r = w1r[0] * w1r[1] - w1i[0] * w1i[1], P11i = w1r[0] * w1i[1] + w1i[0] * w1r[1];

    const int l0 = lane & 1;
    const int l5 = (lane >> 5) & 1;

    float sr[4], si[4];
    // amp[r] = CPsel * Psel:
    // j2 = l0^i1 -> CPa/CPb ; (j0,j1) via l5 -> P pair per r:
    // r0: P00/P11  r1: P11/P00  r2: P01/P10  r3: P10/P01
    {
        float Cr, Ci, Pr, Pi;
        // r = 0 (i0=0,i1=0)
        Cr = l0 ? CPbr : CPar;  Ci = l0 ? CPbi : CPai;
        Pr = l5 ? P11r : P00r;  Pi = l5 ? P11i : P00i;
        sr[0] = Cr * Pr - Ci * Pi;  si[0] = Cr * Pi + Ci * Pr;
        // r = 1 (i0=1,i1=0)
        Pr = l5 ? P00r : P11r;  Pi = l5 ? P00i : P11i;
        sr[1] = Cr * Pr - Ci * Pi;  si[1] = Cr * Pi + Ci * Pr;
        // r = 2 (i0=0,i1=1): j2 = l0^1
        Cr = l0 ? CPar : CPbr;  Ci = l0 ? CPai : CPbi;
        Pr = l5 ? P10r : P01r;  Pi = l5 ? P10i : P01i;
        sr[2] = Cr * Pr - Ci * Pi;  si[2] = Cr * Pi + Ci * Pr;
        // r = 3 (i0=1,i1=1)
        Pr = l5 ? P01r : P10r;  Pi = l5 ? P01i : P10i;
        sr[3] = Cr * Pr - Ci * Pi;  si[3] = Cr * Pi + Ci * Pr;
    }

    // ---- layer 1: gates only; final ring absorbed into measurement ----
    gate_layer(Us + 64, lane, sr, si);

    // ---- measurement (post-ring Z_w == pre-ring Walsh masks; R6-proven) ----
    float p0 = sr[0] * sr[0] + si[0] * si[0];
    float p1 = sr[1] * sr[1] + si[1] * si[1];
    float p2 = sr[2] * sr[2] + si[2] * si[2];
    float p3 = sr[3] * sr[3] + si[3] * si[3];
    float local0  = (p0 + p1) - (p2 + p3);   // (-1)^{i1}
    float local12 = (p0 - p1) - (p2 - p3);   // (-1)^{i0^i1}

    // v[0]: parity-signed full sum of local0
    float a = (__popc(lane) & 1) ? -local0 : local0;
    a += exch<2>(a); a += exch<3>(a); a += exch<4>(a);
    a += exch<5>(a); a += exch<6>(a); a += exch<7>(a);

    // signed WHT butterfly on local12: lane k ends with coeff of mask k
    float x = local12;
    { float t = exch<2>(x); x = (lane & 1)  ? (t - x) : (x + t); }
    { float t = exch<3>(x); x = (lane & 2)  ? (t - x) : (x + t); }
    { float t = exch<4>(x); x = (lane & 4)  ? (t - x) : (x + t); }
    { float t = exch<5>(x); x = (lane & 8)  ? (t - x) : (x + t); }
    { float t = exch<6>(x); x = (lane & 16) ? (t - x) : (x + t); }
    { float t = exch<7>(x); x = (lane & 32) ? (t - x) : (x + t); }

    const int t_ = n >> 15;          // n / B
    const int b_ = n & (B_ - 1);     // n % B
    float* o = qf + b_ * (T_ * D_) + t_ * D_;
    if ((lane & (lane + 1)) == 0) {  // lanes 0,1,3,7,15,31,63
        o[1 + __popc(lane)] = x;     // w = 1..7
        if (lane == 63) o[0] = a;    // w = 0
    }
}

// One wave64 per batch row: h = qf_row @ W1 + b1 ; LayerNorm ; ReLU ; sigmoid(h @ W2 + b2)
__global__ __launch_bounds__(256) void head_kernel(const float* __restrict__ qf,
                                                   const float* __restrict__ W1,
                                                   const float* __restrict__ b1v,
                                                   const float* __restrict__ gam,
                                                   const float* __restrict__ bet,
                                                   const float* __restrict__ W2,
                                                   const float* __restrict__ b2v,
                                                   float* __restrict__ score) {
    const int lane = threadIdx.x & 63;
    int b = (blockIdx.x << 2) + (threadIdx.x >> 6);
    b = __builtin_amdgcn_readfirstlane(b);
    const float* row = qf + b * (T_ * D_);
    float h = b1v[lane];
#pragma unroll
    for (int k = 0; k < T_ * D_; ++k)
        h = fmaf(row[k], W1[(k << 6) + lane], h);
    float t = h;
#pragma unroll
    for (int m = 1; m < 64; m <<= 1) t += __shfl_xor(t, m, 64);
    float mu = t * (1.0f / 64.0f);
    float d = h - mu;
    float vv = d * d;
#pragma unroll
    for (int m = 1; m < 64; m <<= 1) vv += __shfl_xor(vv, m, 64);
    float rs = rsqrtf(vv * (1.0f / 64.0f) + 1e-5f);
    float hn = fmaxf(d * rs * gam[lane] + bet[lane], 0.f);
    float sacc = hn * W2[lane];
#pragma unroll
    for (int m = 1; m < 64; m <<= 1) sacc += __shfl_xor(sacc, m, 64);
    if (lane == 0) score[b] = 1.0f / (1.0f + expf(-(sacc + b2v[0])));
}

extern "C" void kernel_launch(void* const* d_in, const int* in_sizes, int n_in,
                              void* d_out, int out_size, void* d_ws, size_t ws_size,
                              hipStream_t stream) {
    const float* X_seq  = (const float*)d_in[0];
    const float* params = (const float*)d_in[1];
    const float* W1     = (const float*)d_in[2];
    const float* b1v    = (const float*)d_in[3];
    const float* gam    = (const float*)d_in[4];
    const float* bet    = (const float*)d_in[5];
    const float* W2     = (const float*)d_in[6];
    const float* b2v    = (const float*)d_in[7];

    float* out   = (float*)d_out;
    float* score = out;          // B floats
    float* qf    = out + B_;     // B*T*D floats
    float* Us    = (float*)d_ws; // 128 floats

    hipLaunchKernelGGL(precompute_U, dim3(1), dim3(64), 0, stream, params, Us);
    hipLaunchKernelGGL(sim_kernel, dim3(NSAMP / 4), dim3(256), 0, stream, X_seq, Us, qf);
    hipLaunchKernelGGL(head_kernel, dim3(B_ / 4), dim3(256), 0, stream,
                       qf, W1, b1v, gam, bet, W2, b2v, score);
}

// Round 9
// 82.013 us; speedup vs baseline: 11.7561x; 3.6139x over previous
//
#include <hip/hip_runtime.h>
#include <math.h>

#define T_ 10
#define D_ 8
#define B_ 32768
#define NSAMP (T_ * B_)   // 327680

#define DEV static __device__ __forceinline__

// ---------------------------------------------------------------------------
// Precompute (wave-uniform math):
//   WS[0..63]  : combined layer-0 gate U0_w = RZ*RY*RX per wire (8 floats/wire)
//   WS[64..95] : per wire w, B_w = Hadamard transform of A_w = U1_w† Z U1_w,
//                divided by 4: (B00, B11, BR, BI) where
//                B00 = (α+δ+2Reβ)/4, B11 = (α+δ−2Reβ)/4,
//                BR+iBI = Ǎ(1,0)/4 = ((α−δ) − 2i·Imβ)/4.
// ---------------------------------------------------------------------------
__global__ void precompute_U(const float* __restrict__ params, float* __restrict__ WS) {
    int idx = threadIdx.x;
    if (idx >= 16) return;
    float ax = 0.5f*params[idx*3+0], ay = 0.5f*params[idx*3+1], az = 0.5f*params[idx*3+2];
    float cx = cosf(ax), sx = sinf(ax);
    float cy = cosf(ay), sy = sinf(ay);
    float cz = cosf(az), sz = sinf(az);
    // M = RY*RX
    float m00r = cy*cx, m00i = sy*sx;
    float m01r = -sy*cx, m01i = -cy*sx;
    float m10r = sy*cx,  m10i = -cy*sx;
    float m11r = cy*cx,  m11i = -sy*sx;
    // U = RZ*M
    float u00r = cz*m00r + sz*m00i, u00i = cz*m00i - sz*m00r;
    float u01r = cz*m01r + sz*m01i, u01i = cz*m01i - sz*m01r;
    float u10r = cz*m10r - sz*m10i, u10i = cz*m10i + sz*m10r;
    float u11r = cz*m11r - sz*m11i, u11i = cz*m11i + sz*m11r;
    if (idx < 8) {
        float* o = WS + idx*8;
        o[0]=u00r; o[1]=u00i; o[2]=u01r; o[3]=u01i;
        o[4]=u10r; o[5]=u10i; o[6]=u11r; o[7]=u11i;
    } else {
        // A = u† Z u (Hermitian): α=A00, δ=A11 real; β=A01.
        float al = u00r*u00r+u00i*u00i - (u10r*u10r+u10i*u10i);
        float de = u01r*u01r+u01i*u01i - (u11r*u11r+u11i*u11i);
        float br = u00r*u01r+u00i*u01i - (u10r*u11r+u10i*u11i);
        float bi = u00r*u01i-u00i*u01r - (u10r*u11i-u10i*u11r);
        float* o = WS + 64 + (idx-8)*4;
        o[0] = 0.25f*(al+de+2.f*br);
        o[1] = 0.25f*(al+de-2.f*br);
        o[2] = 0.25f*(al-de);
        o[3] = -0.5f*bi;
    }
}

// ---------------------------------------------------------------------------
// One sample per LANE. MPS transfer-matrix contraction, no cross-lane ops.
//   ψ[y] = Π_w v'_w[j_w(y)] (R8-proven permuted product), E_w = <ψ|⊗A^(w)|ψ>.
//   Chain sites 1..7: T̃_k = diag(d_k)·circ(B_k) (Z-type) / diag(d_k)·Π̃0 (I).
//   Nested masks M_w={0..w}, M_0={1..7} (R6-proven) → one prefix chain +
//   scalar suffixes (ρ,τ) + per-w closure with site-0 tensor.
//   Verified by hand: identity circuit; excitation on wire 5 (E_4=cosθ, E_5=1);
//   excitation on wire 1 (E_1=1).
// ---------------------------------------------------------------------------
__global__ __launch_bounds__(256) void sim_kernel(const float* __restrict__ X,
                                                  const float* __restrict__ WS,
                                                  float* __restrict__ qf) {
    const int n = blockIdx.x*256 + threadIdx.x;
    const float* xp = X + n*8;
    float xr[8];
    { float4 t0 = *(const float4*)xp; float4 t1 = *(const float4*)(xp+4);
      xr[0]=t0.x; xr[1]=t0.y; xr[2]=t0.z; xr[3]=t0.w;
      xr[4]=t1.x; xr[5]=t1.y; xr[6]=t1.z; xr[7]=t1.w; }

    // Per-wire: v'_w = U0_w · (c²−ics, cs+is²); D± = v'0 ± v'1;
    // d_w = (|D+|², D+·conj(D−), conj, |D−|²). Wire 0 → G (closure).
    float d0v[7], d3v[7], dRr[7], dRi[7];
    float G00, G11, G01r, G01i;
#pragma unroll
    for (int w = 0; w < 8; ++w) {
        float th = 0.5f*xr[w];
        float c = __cosf(th), s = __sinf(th);
        float a0r = c*c, a0i = -c*s, a1r = c*s, a1i = s*s;
        const float* u = WS + 8*w;
        float f0r = u[0]*a0r - u[1]*a0i + u[2]*a1r - u[3]*a1i;
        float f0i = u[0]*a0i + u[1]*a0r + u[2]*a1i + u[3]*a1r;
        float f1r = u[4]*a0r - u[5]*a0i + u[6]*a1r - u[7]*a1i;
        float f1i = u[4]*a0i + u[5]*a0r + u[6]*a1i + u[7]*a1r;
        float Dpr=f0r+f1r, Dpi=f0i+f1i, Dmr=f0r-f1r, Dmi=f0i-f1i;
        float m00 = Dpr*Dpr+Dpi*Dpi;
        float m11 = Dmr*Dmr+Dmi*Dmi;
        float mr  = Dpr*Dmr+Dpi*Dmi;   // Re(D+ conj(D−))
        float mi  = Dpi*Dmr-Dpr*Dmi;   // Im(D+ conj(D−))
        if (w==0) { G00=m00; G11=m11; G01r=mr; G01i=mi; }
        else { d0v[w-1]=m00; d3v[w-1]=m11; dRr[w-1]=mr; dRi[w-1]=mi; }
    }

    // Suffix scalars: Rs[w-1] = Π_{k=w+2..7} ρ_k, Ts[w-1] = Π τ_k
    // (ρ = 0.5(d0+d3), τ = Re d1 — collapsed interior I-sites).
    float Rs[6], Ts[6];
    Rs[5]=1.f; Ts[5]=1.f;
#pragma unroll
    for (int w = 5; w >= 1; --w) {
        float rho = 0.5f*(d0v[w+1]+d3v[w+1]);
        float tau = dRr[w+1];
        Rs[w-1]=Rs[w]*rho; Ts[w-1]=Ts[w]*tau;
    }

    const float Gr[4] = {G00, G01r, G01r, G11};
    const float Gi[4] = {0.f, G01i, -G01i, 0.f};
    const float B0r[4] = {WS[64], WS[66], WS[66], WS[65]};
    const float B0i[4] = {0.f, -WS[67], WS[67], 0.f};

    // Y[m][x] = 0.5*(G[x]*B0[m] + G[x^3]*B0[m^3])  (Π̃0-folded site-0 closure)
    float Yr[4][4], Yi[4][4];
#pragma unroll
    for (int m = 0; m < 4; ++m)
#pragma unroll
    for (int x = 0; x < 4; ++x) {
        int x3 = x^3, m3 = m^3;
        float t1r = Gr[x]*B0r[m] - Gi[x]*B0i[m];
        float t1i = Gr[x]*B0i[m] + Gi[x]*B0r[m];
        float t2r = Gr[x3]*B0r[m3] - Gi[x3]*B0i[m3];
        float t2i = Gr[x3]*B0i[m3] + Gi[x3]*B0r[m3];
        Yr[m][x] = 0.5f*(t1r+t2r);
        Yi[m][x] = 0.5f*(t1i+t2i);
    }

    float Ev[8];
    float Mr[4][4], Mi[4][4];

    // chain init: M = diag(d_1)·circ(B_1)
    {
        const float* Bp = WS + 64 + 4;
        float Br_[4] = {Bp[0], Bp[2], Bp[2], Bp[1]};
        float Bi_[4] = {0.f, -Bp[3], Bp[3], 0.f};
        float dr_[4] = {d0v[0], dRr[0], dRr[0], d3v[0]};
        float di_[4] = {0.f, dRi[0], -dRi[0], 0.f};
#pragma unroll
        for (int r = 0; r < 4; ++r)
#pragma unroll
        for (int c = 0; c < 4; ++c) {
            int idx = r^c;
            Mr[r][c] = dr_[r]*Br_[idx] - di_[r]*Bi_[idx];
            Mi[r][c] = dr_[r]*Bi_[idx] + di_[r]*Br_[idx];
        }
    }

#pragma unroll
    for (int wi = 1; wi <= 7; ++wi) {
        if (wi <= 6) {
            // E_wi = Tr[M · diag(e) · Π̃0 · T̃0^Z], e = d_{wi+1} ⊙ (R,T,T,R)
            const int k = wi;
            float eR = Rs[wi-1], eT = Ts[wi-1];
            float er_[4] = {d0v[k]*eR, dRr[k]*eT, dRr[k]*eT, d3v[k]*eR};
            float ei_[4] = {0.f, dRi[k]*eT, -dRi[k]*eT, 0.f};
            float E = 0.f;
#pragma unroll
            for (int m = 0; m < 4; ++m) {
                float Sr=0.f, Si=0.f;
#pragma unroll
                for (int r = 0; r < 4; ++r) {
                    int x = m^r;
                    Sr += Mr[r][m]*Yr[m][x] - Mi[r][m]*Yi[m][x];
                    Si += Mr[r][m]*Yi[m][x] + Mi[r][m]*Yr[m][x];
                }
                E += er_[m]*Sr - ei_[m]*Si;
            }
            Ev[wi] = E;
        } else {
            // wi==7: E_7 = Tr[M·T̃0^Z]; E_0 = Tr[M·T̃0^I]
            float E7 = 0.f, E0 = 0.f;
#pragma unroll
            for (int m = 0; m < 4; ++m)
#pragma unroll
            for (int r = 0; r < 4; ++r) {
                int x = m^r;
                float tr = Gr[x]*B0r[m] - Gi[x]*B0i[m];
                float ti = Gr[x]*B0i[m] + Gi[x]*B0r[m];
                E7 += Mr[r][m]*tr - Mi[r][m]*ti;
                if (m==0 || m==3)
                    E0 += 0.5f*(Mr[r][m]*Gr[x] - Mi[r][m]*Gi[x]);
            }
            Ev[7] = E7; Ev[0] = E0;
        }
        if (wi == 7) break;
        // M ← M · diag(d_{wi+1}) · circ(B_{wi+1})
        {
            const int k = wi;
            const float* Bp = WS + 64 + 4*(wi+1);
            float Br_[4] = {Bp[0], Bp[2], Bp[2], Bp[1]};
            float Bi_[4] = {0.f, -Bp[3], Bp[3], 0.f};
            float dr_[4] = {d0v[k], dRr[k], dRr[k], d3v[k]};
            float di_[4] = {0.f, dRi[k], -dRi[k], 0.f};
            float Nr[4][4], Ni[4][4];
#pragma unroll
            for (int r = 0; r < 4; ++r)
#pragma unroll
            for (int m = 0; m < 4; ++m) {
                Nr[r][m] = Mr[r][m]*dr_[m] - Mi[r][m]*di_[m];
                Ni[r][m] = Mr[r][m]*di_[m] + Mi[r][m]*dr_[m];
            }
#pragma unroll
            for (int r = 0; r < 4; ++r)
#pragma unroll
            for (int c = 0; c < 4; ++c) {
                float ar = 0.f, ai = 0.f;
#pragma unroll
                for (int m = 0; m < 4; ++m) {
                    int idx = m^c;
                    ar += Nr[r][m]*Br_[idx] - Ni[r][m]*Bi_[idx];
                    ai += Nr[r][m]*Bi_[idx] + Ni[r][m]*Br_[idx];
                }
                Mr[r][c] = ar; Mi[r][c] = ai;
            }
        }
    }

    const int t_ = n >> 15;          // n / B
    const int b_ = n & (B_-1);       // n % B
    float* o = qf + b_*(T_*D_) + t_*D_;
    float4 o0 = {Ev[0], Ev[1], Ev[2], Ev[3]};
    float4 o1 = {Ev[4], Ev[5], Ev[6], Ev[7]};
    *(float4*)o = o0;
    *(float4*)(o+4) = o1;
}

// One wave64 per batch row: h = qf_row @ W1 + b1 ; LayerNorm ; ReLU ; sigmoid(h @ W2 + b2)
__global__ __launch_bounds__(256) void head_kernel(const float* __restrict__ qf,
                                                   const float* __restrict__ W1,
                                                   const float* __restrict__ b1v,
                                                   const float* __restrict__ gam,
                                                   const float* __restrict__ bet,
                                                   const float* __restrict__ W2,
                                                   const float* __restrict__ b2v,
                                                   float* __restrict__ score) {
    const int lane = threadIdx.x & 63;
    int b = (blockIdx.x << 2) + (threadIdx.x >> 6);
    b = __builtin_amdgcn_readfirstlane(b);
    const float* row = qf + b * (T_ * D_);
    float h = b1v[lane];
#pragma unroll
    for (int k = 0; k < T_ * D_; ++k)
        h = fmaf(row[k], W1[(k << 6) + lane], h);
    float t = h;
#pragma unroll
    for (int m = 1; m < 64; m <<= 1) t += __shfl_xor(t, m, 64);
    float mu = t * (1.0f / 64.0f);
    float d = h - mu;
    float vv = d * d;
#pragma unroll
    for (int m = 1; m < 64; m <<= 1) vv += __shfl_xor(vv, m, 64);
    float rs = rsqrtf(vv * (1.0f / 64.0f) + 1e-5f);
    float hn = fmaxf(d * rs * gam[lane] + bet[lane], 0.f);
    float sacc = hn * W2[lane];
#pragma unroll
    for (int m = 1; m < 64; m <<= 1) sacc += __shfl_xor(sacc, m, 64);
    if (lane == 0) score[b] = 1.0f / (1.0f + expf(-(sacc + b2v[0])));
}

extern "C" void kernel_launch(void* const* d_in, const int* in_sizes, int n_in,
                              void* d_out, int out_size, void* d_ws, size_t ws_size,
                              hipStream_t stream) {
    const float* X_seq  = (const float*)d_in[0];
    const float* params = (const float*)d_in[1];
    const float* W1     = (const float*)d_in[2];
    const float* b1v    = (const float*)d_in[3];
    const float* gam    = (const float*)d_in[4];
    const float* bet    = (const float*)d_in[5];
    const float* W2     = (const float*)d_in[6];
    const float* b2v    = (const float*)d_in[7];

    float* out   = (float*)d_out;
    float* score = out;          // B floats
    float* qf    = out + B_;     // B*T*D floats
    float* WS    = (float*)d_ws; // 96 floats

    hipLaunchKernelGGL(precompute_U, dim3(1), dim3(64), 0, stream, params, WS);
    hipLaunchKernelGGL(sim_kernel, dim3(NSAMP / 256), dim3(256), 0, stream, X_seq, WS, qf);
    hipLaunchKernelGGL(head_kernel, dim3(B_ / 4), dim3(256), 0, stream,
                       qf, W1, b1v, gam, bet, W2, b2v, score);
}